// Round 5
// baseline (697.935 us; speedup 1.0000x reference)
//
#include <hip/hip_runtime.h>
#include <math.h>

// Problem constants (from reference: B=8, T=4096, D=1024, fp32)
#define BB 8
#define TT 4096
#define DD 1024
#define NC 256            // chunks per batch
#define CT (TT / NC)      // chunk length = 16
#define D4 (DD / 4)       // float4s per row = 256

// ws layout (floats):
//   [0, BB*NC*DD)   per-chunk aggregates agg[B][NC][D]  (8 MB)
//   [BB*NC*DD, ..)  control: flags[BB*NC] + ticket (ints, 8.2 KB)
#define AGG_OFF 0
#define CTL_OFF (BB * NC * DD)

typedef float vfloat4 __attribute__((ext_vector_type(4)));

__device__ __forceinline__ float gelu_exact(float v) {
    // exact GELU: 0.5*v*(1+erf(v/sqrt(2)))
    return 0.5f * v * (1.0f + erff(v * 0.70710678118654752f));
}

__device__ __forceinline__ void gelu_acc(float4& s, const float4 v) {
    s.x += gelu_exact(v.x);
    s.y += gelu_exact(v.y);
    s.z += gelu_exact(v.z);
    s.w += gelu_exact(v.w);
}

__device__ __forceinline__ void f4_acc(float4& s, const float4 a) {
    s.x += a.x; s.y += a.y; s.z += a.z; s.w += a.w;
}

// ---------------------------------------------------------------------------
// Single-pass masked causal chunk-prefix, aggregate-only decoupled lookback.
//
// Protocol (per valid chunk tk=(b,c)):
//   Phase A : gelu-sum own 16 rows  -> plain stores to agg[tk]
//   publish : __threadfence (agent release) ; __syncthreads ;
//             thread0 RELEASE-stores flags[tk]=1
//   wait    : parallel poll (thread i watches flags[b,i], i<c) until ALL
//             predecessors published; __threadfence (acquire side)
//   lookback: pre = sum of agg[b,0..c-1]   (L2 traffic, R2-proven ~free)
//   apply   : re-read own rows (L3-warm from Phase A), running prefix,
//             nontemporal store out
//
// Deadlock-freedom: work ids come from an atomic ticket => ticket order ==
// block start order. Chunk (b,c) waits only on (b,cc<c), i.e. strictly
// smaller tickets, i.e. blocks that started earlier (running or finished) —
// each publishes its flag BEFORE any waiting. Fully-masked chunks
// (t0>=len) never publish and are never waited on: a waiter has t0<len,
// so all its predecessors have t0_cc < t0 < len (all valid).
// ---------------------------------------------------------------------------
__global__ __launch_bounds__(256)
void k_onepass(const float* __restrict__ x, const int* __restrict__ lengths,
               float* __restrict__ ws, float* __restrict__ out) {
    float* agg    = ws + AGG_OFF;
    int*   flags  = (int*)(ws + CTL_OFF);   // 0=empty, 1=aggregate ready
    int*   ticket = flags + BB * NC;

    __shared__ int s_tk;
    __shared__ int s_nr;
    if (threadIdx.x == 0)
        s_tk = __hip_atomic_fetch_add(ticket, 1, __ATOMIC_RELAXED,
                                      __HIP_MEMORY_SCOPE_AGENT);
    __syncthreads();
    const int tk  = s_tk;          // == b*NC + c
    const int b   = tk >> 8;       // NC == 256
    const int c   = tk & (NC - 1);
    const int d4  = threadIdx.x;   // float4 column
    const int len = lengths[b];
    const int t0  = c * CT;
    const int tv  = min(t0 + CT, len);

    const float4* __restrict__ xp = (const float4*)(x + (size_t)b * TT * DD);
    vfloat4* __restrict__ op = (vfloat4*)(out + (size_t)b * TT * DD);

    int t = t0;
    if (t0 < len) {
        // -------- Phase A: chunk-local masked gelu aggregate --------
        float4 s = make_float4(0.f, 0.f, 0.f, 0.f);
        #pragma unroll 4
        for (int tt = t0; tt < tv; ++tt) {
            float4 v = xp[(size_t)tt * D4 + d4];
            gelu_acc(s, v);
        }
        ((float4*)agg)[(size_t)tk * D4 + d4] = s;

        // -------- publish: release payload, then flag --------
        __threadfence();           // agent-scope release fence (all threads)
        __syncthreads();           // all payload stores happen-before flag
        if (threadIdx.x == 0)
            __hip_atomic_store(&flags[tk], 1, __ATOMIC_RELEASE,
                               __HIP_MEMORY_SCOPE_AGENT);

        // -------- wait for ALL predecessor aggregates --------
        float4 pre = make_float4(0.f, 0.f, 0.f, 0.f);
        if (c > 0) {
            for (;;) {
                if (threadIdx.x == 0) s_nr = 0;
                __syncthreads();
                bool ok = true;
                if ((int)threadIdx.x < c) {
                    int f = __hip_atomic_load(&flags[(b << 8) + threadIdx.x],
                                              __ATOMIC_ACQUIRE,
                                              __HIP_MEMORY_SCOPE_AGENT);
                    ok = (f != 0);
                }
                if (!ok) s_nr = 1;          // benign LDS race (same value)
                __syncthreads();
                if (s_nr == 0) break;
                __builtin_amdgcn_s_sleep(2);
            }
            __threadfence();       // acquire side: payload loads after flags

            // -------- lookback: sum predecessor aggregates (L2) --------
            const float4* __restrict__ aggp =
                (const float4*)agg + (size_t)(b << 8) * D4 + d4;
            float4 p1 = make_float4(0.f, 0.f, 0.f, 0.f);
            int cc = 0;
            #pragma unroll 4
            for (; cc + 1 < c; cc += 2) {
                float4 a0 = aggp[(size_t)cc * D4];
                float4 a1 = aggp[(size_t)(cc + 1) * D4];
                f4_acc(pre, a0);
                f4_acc(p1, a1);
            }
            if (cc < c) f4_acc(pre, aggp[(size_t)cc * D4]);
            f4_acc(pre, p1);
        }

        // -------- apply: rows are L3-warm from Phase A --------
        #pragma unroll 4
        for (; t < tv; ++t) {
            float4 v = xp[(size_t)t * D4 + d4];
            gelu_acc(pre, v);
            vfloat4 o = {v.x + pre.x, v.y + pre.y, v.z + pre.z, v.w + pre.w};
            __builtin_nontemporal_store(o, &op[(size_t)t * D4 + d4]);
        }
    }
    // rows at/after length: plain copy (mask is 0)
    #pragma unroll 4
    for (; t < t0 + CT; ++t) {
        float4 v = xp[(size_t)t * D4 + d4];
        vfloat4 o = {v.x, v.y, v.z, v.w};
        __builtin_nontemporal_store(o, &op[(size_t)t * D4 + d4]);
    }
}

extern "C" void kernel_launch(void* const* d_in, const int* in_sizes, int n_in,
                              void* d_out, int out_size, void* d_ws, size_t ws_size,
                              hipStream_t stream) {
    const float* x       = (const float*)d_in[0];
    const int*   lengths = (const int*)d_in[1];
    float*       out     = (float*)d_out;
    float*       ws      = (float*)d_ws;   // needs 8 MB + 8.2 KB

    // zero flags + ticket each launch (ws is re-poisoned between iterations)
    hipMemsetAsync((char*)ws + (size_t)CTL_OFF * sizeof(float), 0,
                   (BB * NC + 1) * sizeof(int), stream);

    dim3 blk(256, 1, 1);
    dim3 grd(NC * BB, 1, 1);   // 2048 blocks, ticket-ordered
    hipLaunchKernelGGL(k_onepass, grd, blk, 0, stream, x, lengths, ws, out);
}

// Round 6
// 255.954 us; speedup vs baseline: 2.7268x; 2.7268x over previous
//
#include <hip/hip_runtime.h>
#include <math.h>

// Problem constants (from reference: B=8, T=4096, D=1024, fp32)
#define BB 8
#define TT 4096
#define DD 1024
#define NC 256           // number of T-chunks
#define CT (TT / NC)     // chunk length = 16
#define D4 (DD / 4)      // float4s per row = 256

// native clang vector type — accepted by __builtin_nontemporal_store
typedef float vfloat4 __attribute__((ext_vector_type(4)));

// Fast exact-GELU: erf via Abramowitz-Stegun 7.1.26 (max abs err 1.5e-7,
// ~= fp32 eps) with hw rcp + hw exp2-based __expf. ~14 VALU ops vs ~30 for
// libm erff. k_partial is VALU-bound (gelu cost ~2x its 11us BW time), so
// this converts it to BW-bound.
__device__ __forceinline__ float gelu_fast(float v) {
    const float x  = v * 0.70710678118654752f;   // v / sqrt(2)
    const float ax = fabsf(x);
    const float t  = __builtin_amdgcn_rcpf(fmaf(0.3275911f, ax, 1.0f));
    float p = fmaf(1.061405429f, t, -1.453152027f);
    p = fmaf(p, t, 1.421413741f);
    p = fmaf(p, t, -0.284496736f);
    p = fmaf(p, t, 0.254829592f);
    const float e  = __expf(-ax * ax);
    const float er = fmaf(-p * t, e, 1.0f);      // erf(|x|)
    const float erf_x = copysignf(er, x);
    return 0.5f * v * (1.0f + erf_x);
}

__device__ __forceinline__ void gelu_acc(float4& s, const float4 v) {
    s.x += gelu_fast(v.x);
    s.y += gelu_fast(v.y);
    s.z += gelu_fast(v.z);
    s.w += gelu_fast(v.w);
}

__device__ __forceinline__ void f4_acc(float4& s, const float4 a) {
    s.x += a.x; s.y += a.y; s.z += a.z; s.w += a.w;
}

// ---------------------------------------------------------------------------
// Pass 1: per-(b,chunk) masked sums of gelu(x) over the chunk's T range.
// ws layout: [B][NC][D] floats (8 MB). 2048 blocks -> full occupancy.
// Fully-masked chunks skip the store: their aggregates are never read
// (a reader chunk c has t0<len, so all its predecessors have t0_cc<len).
// ---------------------------------------------------------------------------
__global__ __launch_bounds__(256)
void k_partial(const float* __restrict__ x, const int* __restrict__ lengths,
               float* __restrict__ ws) {
    const int c  = blockIdx.x;       // chunk
    const int b  = blockIdx.y;       // batch
    const int d4 = threadIdx.x;      // 0..255 (float4 column)
    const int len = lengths[b];
    const int t0 = c * CT;
    if (t0 >= len) return;           // fully-masked chunk: aggregate unused
    const int t1 = min(t0 + CT, len);

    const float4* __restrict__ xp = (const float4*)(x + (size_t)b * TT * DD);
    float4 s = make_float4(0.f, 0.f, 0.f, 0.f);
    #pragma unroll 4
    for (int t = t0; t < t1; ++t) {
        float4 v = xp[(size_t)t * D4 + d4];
        gelu_acc(s, v);
    }
    ((float4*)ws)[((size_t)b * NC + c) * D4 + d4] = s;
}

// ---------------------------------------------------------------------------
// Pass 2 (fused scan+apply): each block sums the c predecessor aggregates
// directly (ws is 8 MB, L2/L3-resident; R2/R4 A/B showed this O(NC^2) cache
// traffic is fully hidden under the HBM stream), then re-reads the chunk's
// x rows (L3-warm from pass 1), adds the gelu running prefix, and
// nontemporal-stores out. 2048 blocks, 32 waves/CU.
// ---------------------------------------------------------------------------
__global__ __launch_bounds__(256)
void k_apply(const float* __restrict__ x, const int* __restrict__ lengths,
             const float* __restrict__ ws, float* __restrict__ out) {
    const int c  = blockIdx.x;
    const int b  = blockIdx.y;
    const int d4 = threadIdx.x;
    const int len = lengths[b];
    const int t0 = c * CT;
    const int tv = min(t0 + CT, len);   // valid (masked-in) end

    const float4* __restrict__ xp = (const float4*)(x + (size_t)b * TT * DD);
    vfloat4* __restrict__ op = (vfloat4*)(out + (size_t)b * TT * DD);

    int t = t0;
    if (t0 < len) {
        // ---- exclusive prefix over preceding chunk aggregates ----
        float4 p0 = make_float4(0.f, 0.f, 0.f, 0.f);
        float4 p1 = make_float4(0.f, 0.f, 0.f, 0.f);
        const float4* __restrict__ aggp =
            (const float4*)ws + (size_t)b * NC * D4 + d4;
        int cc = 0;
        #pragma unroll 4
        for (; cc + 1 < c; cc += 2) {
            float4 a0 = aggp[(size_t)cc * D4];
            float4 a1 = aggp[(size_t)(cc + 1) * D4];
            f4_acc(p0, a0);
            f4_acc(p1, a1);
        }
        if (cc < c) f4_acc(p0, aggp[(size_t)cc * D4]);
        float4 pre = make_float4(p0.x + p1.x, p0.y + p1.y,
                                 p0.z + p1.z, p0.w + p1.w);

        // ---- apply: running inclusive prefix over the chunk ----
        #pragma unroll 4
        for (; t < tv; ++t) {
            float4 v = xp[(size_t)t * D4 + d4];
            gelu_acc(pre, v);
            vfloat4 o = {v.x + pre.x, v.y + pre.y, v.z + pre.z, v.w + pre.w};
            __builtin_nontemporal_store(o, &op[(size_t)t * D4 + d4]);
        }
    }
    // rows at/after length: plain copy (mask is 0)
    #pragma unroll 4
    for (; t < t0 + CT; ++t) {
        float4 v = xp[(size_t)t * D4 + d4];
        vfloat4 o = {v.x, v.y, v.z, v.w};
        __builtin_nontemporal_store(o, &op[(size_t)t * D4 + d4]);
    }
}

extern "C" void kernel_launch(void* const* d_in, const int* in_sizes, int n_in,
                              void* d_out, int out_size, void* d_ws, size_t ws_size,
                              hipStream_t stream) {
    const float* x       = (const float*)d_in[0];
    const int*   lengths = (const int*)d_in[1];
    float*       out     = (float*)d_out;
    float*       ws      = (float*)d_ws;   // needs B*NC*D*4 = 8 MB

    dim3 blk(256, 1, 1);
    dim3 g1(NC, BB, 1);
    hipLaunchKernelGGL(k_partial, g1, blk, 0, stream, x, lengths, ws);
    hipLaunchKernelGGL(k_apply,   g1, blk, 0, stream, x, lengths, ws, out);
}

// Round 7
// 243.565 us; speedup vs baseline: 2.8655x; 1.0509x over previous
//
#include <hip/hip_runtime.h>
#include <math.h>

// Problem constants (from reference: B=8, T=4096, D=1024, fp32)
#define BB 8
#define TT 4096
#define DD 1024
#define NC 256           // 16-row chunks per batch (k_apply granularity)
#define CT (TT / NC)     // chunk length = 16
#define D4 (DD / 4)      // float4s per row = 256
#define NCS 128          // superchunks per batch (k_partial granularity)
#define CPS 2            // chunks per superchunk
#define CTS (CT * CPS)   // superchunk rows = 32

// ws layout: agg[B][NC][D] floats (8 MB).
// agg[b][2k]   = masked gelu-sum of chunk 2k          (first half of super k)
// agg[b][2k+1] = masked gelu-sum of chunks 2k..2k+1   (full 32-row super k)
// (within-superchunk running inclusive, stored by k_partial)

typedef float vfloat4 __attribute__((ext_vector_type(4)));

// Fast exact-GELU: erf via Abramowitz-Stegun 7.1.26 (max abs err 1.5e-7,
// ~= fp32 eps) with hw rcp + hw exp. Verified in R6 (passed, same absmax).
__device__ __forceinline__ float gelu_fast(float v) {
    const float x  = v * 0.70710678118654752f;   // v / sqrt(2)
    const float ax = fabsf(x);
    const float t  = __builtin_amdgcn_rcpf(fmaf(0.3275911f, ax, 1.0f));
    float p = fmaf(1.061405429f, t, -1.453152027f);
    p = fmaf(p, t, 1.421413741f);
    p = fmaf(p, t, -0.284496736f);
    p = fmaf(p, t, 0.254829592f);
    const float e  = __expf(-ax * ax);
    const float er = fmaf(-p * t, e, 1.0f);      // erf(|x|)
    const float erf_x = copysignf(er, x);
    return 0.5f * v * (1.0f + erf_x);
}

__device__ __forceinline__ void gelu_acc(float4& s, const float4 v) {
    s.x += gelu_fast(v.x);
    s.y += gelu_fast(v.y);
    s.z += gelu_fast(v.z);
    s.w += gelu_fast(v.w);
}

__device__ __forceinline__ void f4_acc(float4& s, const float4 a) {
    s.x += a.x; s.y += a.y; s.z += a.z; s.w += a.w;
}

// ---------------------------------------------------------------------------
// Pass 1: per-(b,superchunk) masked gelu running sums over 32 rows, storing
// the running inclusive at each 16-row chunk boundary. 1024 blocks.
// Skip whole superchunk iff its first row >= len: any reader of agg[b][j]
// has its own t0 > 16*j and t0 < len, so superchunk j>>1 starts < len and
// was not skipped. Partially-valid superchunks store the masked running sum
// unconditionally at both boundaries (exactly the value readers need).
// ---------------------------------------------------------------------------
__global__ __launch_bounds__(256)
void k_partial(const float* __restrict__ x, const int* __restrict__ lengths,
               float* __restrict__ ws) {
    const int s  = blockIdx.x;       // superchunk
    const int b  = blockIdx.y;       // batch
    const int d4 = threadIdx.x;      // 0..255 (float4 column)
    const int len = lengths[b];
    const int t0s = s * CTS;
    if (t0s >= len) return;          // aggregates provably never read

    const float4* __restrict__ xp = (const float4*)(x + (size_t)b * TT * DD);
    float4* __restrict__ aggw =
        (float4*)ws + ((size_t)b * NC + (size_t)s * CPS) * D4 + d4;

    float4 run = make_float4(0.f, 0.f, 0.f, 0.f);
    #pragma unroll
    for (int j = 0; j < CPS; ++j) {
        const int tj0 = t0s + j * CT;
        const int tj1 = min(tj0 + CT, len);   // may be <= tj0 (empty)
        #pragma unroll 4
        for (int t = tj0; t < tj1; ++t) {
            float4 v = xp[(size_t)t * D4 + d4];
            gelu_acc(run, v);
        }
        aggw[(size_t)j * D4] = run;           // running inclusive
    }
}

// ---------------------------------------------------------------------------
// Pass 2 (fused scan+apply): preload the chunk's 16 rows into registers
// (16 independent dwordx4 loads issue first; their HBM latency hides under
// the lookback), compute the exclusive chunk prefix from 32-row aggregates
// (odd-indexed, stride-2: <=127+1 loads, L2-resident), then run the
// register-resident gelu prefix and nontemporal-store out. 2048 blocks.
// ---------------------------------------------------------------------------
__global__ __launch_bounds__(256)
void k_apply(const float* __restrict__ x, const int* __restrict__ lengths,
             const float* __restrict__ ws, float* __restrict__ out) {
    const int c  = blockIdx.x;
    const int b  = blockIdx.y;
    const int d4 = threadIdx.x;
    const int len = lengths[b];
    const int t0 = c * CT;
    const int tv = min(t0 + CT, len);   // valid (masked-in) end

    const float4* __restrict__ xp = (const float4*)(x + (size_t)b * TT * DD);
    vfloat4* __restrict__ op = (vfloat4*)(out + (size_t)b * TT * DD);

    // ---- preload all CT rows (independent loads, overlap with lookback) ----
    float4 r[CT];
    #pragma unroll
    for (int i = 0; i < CT; ++i)
        r[i] = xp[(size_t)(t0 + i) * D4 + d4];

    // ---- exclusive prefix from 32-row aggregates + <=1 fine aggregate ----
    float4 pre = make_float4(0.f, 0.f, 0.f, 0.f);
    if (t0 < len && c > 0) {
        const float4* __restrict__ aggp =
            (const float4*)ws + (size_t)b * NC * D4 + d4;
        const int sc = c >> 1;          // complete superchunks before c
        float4 p1 = make_float4(0.f, 0.f, 0.f, 0.f);
        int ss = 0;
        #pragma unroll 4
        for (; ss + 1 < sc; ss += 2) {
            f4_acc(pre, aggp[(size_t)(2 * ss + 1) * D4]);
            f4_acc(p1,  aggp[(size_t)(2 * ss + 3) * D4]);
        }
        if (ss < sc) f4_acc(pre, aggp[(size_t)(2 * ss + 1) * D4]);
        if (c & 1)   f4_acc(pre, aggp[(size_t)(c - 1) * D4]);
        f4_acc(pre, p1);
    }

    // ---- apply from registers: running prefix on valid rows, copy after ----
    #pragma unroll
    for (int i = 0; i < CT; ++i) {
        const int t = t0 + i;
        const float4 v = r[i];
        vfloat4 o;
        if (t < tv) {                   // wave-uniform branch
            gelu_acc(pre, v);
            o = {v.x + pre.x, v.y + pre.y, v.z + pre.z, v.w + pre.w};
        } else {
            o = {v.x, v.y, v.z, v.w};
        }
        __builtin_nontemporal_store(o, &op[(size_t)t * D4 + d4]);
    }
}

extern "C" void kernel_launch(void* const* d_in, const int* in_sizes, int n_in,
                              void* d_out, int out_size, void* d_ws, size_t ws_size,
                              hipStream_t stream) {
    const float* x       = (const float*)d_in[0];
    const int*   lengths = (const int*)d_in[1];
    float*       out     = (float*)d_out;
    float*       ws      = (float*)d_ws;   // needs B*NC*D*4 = 8 MB

    dim3 blk(256, 1, 1);
    dim3 g1(NCS, BB, 1);   // 1024 blocks (32-row superchunks)
    hipLaunchKernelGGL(k_partial, g1, blk, 0, stream, x, lengths, ws);

    dim3 g2(NC, BB, 1);    // 2048 blocks (16-row chunks)
    hipLaunchKernelGGL(k_apply, g2, blk, 0, stream, x, lengths, ws, out);
}